// Round 1
// baseline (5835.382 us; speedup 1.0000x reference)
//
#include <hip/hip_runtime.h>
#include <hip/hip_bf16.h>
#include <stdint.h>

// ---------------------------------------------------------------------------
// CustomSimpleGRU: 2-layer GRU-variant (reset gate unused), B=128, S=512,
// IN=128, H=1024.  Persistent-kernel design:
//   - 192 WGs x 256 threads, 160KB LDS each -> exactly 1 WG/CU, all resident.
//   - WGs 0..63:  layer0, g=wg&1 (batch half, M=64), blk=wg>>1 (32 blocks of
//                 N=64 gate cols = 32 (z,n) pairs).  K=1152 (x|h0).
//   - WGs 64..191: layer1, g, blk in [0,64) (N=32 = 16 pairs). K=2048 (h0|h1).
//   - Phase p: L0 computes t=p, L1 computes t=p-1 (pipelined) -> ONE global
//     barrier per phase, 513 phases.
//   - Weights: useful (z,n) columns converted to bf16, stored transposed
//     [n][k] in LDS with XOR swizzle (byte ^= (row&7)<<4), loaded once.
//   - h0/h1 ping-pong bf16 buffers in ws; cross-XCD coherence via sc0 sc1
//     bypass loads/stores (LLC), so no cache invalidates anywhere.
//   - Per-WG: K split over 4 waves (no redundant A/B traffic), LDS reduction,
//     wave q owns M-tile q; h_old kept in registers across all steps.
// ---------------------------------------------------------------------------

#define SEQLEN 512
#define INDIM  128

typedef short bhalf8 __attribute__((ext_vector_type(8)));
typedef float f32x4  __attribute__((ext_vector_type(4)));

#define WS_H0B 4096                    // 2 slots x 128*1024 bf16
#define WS_H1B (WS_H0B + 2*262144)
#define WS_H1F (WS_H1B + 2*262144)     // fp32 master of h1 (for predictions)
#define WS_END (WS_H1F + 524288)
#define LDS_BYTES 163840               // 147456 weights + 16384 reduce staging

__device__ __forceinline__ unsigned int bfbits(float f) {
  __hip_bfloat16 h = __float2bfloat16(f);
  unsigned short u; __builtin_memcpy(&u, &h, 2);
  return (unsigned int)u;
}

template<int N> __device__ __forceinline__ void waitvm() {
  asm volatile("s_waitcnt vmcnt(%0)" :: "n"(N));
}

// LLC-coherent (cross-XCD) bypass ops
#define GLOADA(dst, p)  asm volatile("global_load_dwordx4 %0, %1, off sc0 sc1" : "=v"(dst) : "v"((unsigned long long)(p)))
#define STORE_BF16(p, u) asm volatile("global_store_short %0, %1, off sc0 sc1" :: "v"((unsigned long long)(p)), "v"(u))
#define STORE_F32(p, f)  asm volatile("global_store_dword %0, %1, off sc0 sc1" :: "v"((unsigned long long)(p)), "v"(f))

// Tie the loaded A-frags to the waitcnt so MFMAs cannot be scheduled above it.
#define ATIE(sI) asm volatile("" : "+v"(af[sI][0]), "+v"(af[sI][1]), "+v"(af[sI][2]), "+v"(af[sI][3]))

#define MFMA4(ntI, bx, sI) \
  acc[0][ntI] = __builtin_amdgcn_mfma_f32_16x16x32_bf16(af[sI][0], bx, acc[0][ntI], 0,0,0); \
  acc[1][ntI] = __builtin_amdgcn_mfma_f32_16x16x32_bf16(af[sI][1], bx, acc[1][ntI], 0,0,0); \
  acc[2][ntI] = __builtin_amdgcn_mfma_f32_16x16x32_bf16(af[sI][2], bx, acc[2][ntI], 0,0,0); \
  acc[3][ntI] = __builtin_amdgcn_mfma_f32_16x16x32_bf16(af[sI][3], bx, acc[3][ntI], 0,0,0);

#define MFMA4X(ntI, bx) \
  acc[0][ntI] = __builtin_amdgcn_mfma_f32_16x16x32_bf16(ax[0], bx, acc[0][ntI], 0,0,0); \
  acc[1][ntI] = __builtin_amdgcn_mfma_f32_16x16x32_bf16(ax[1], bx, acc[1][ntI], 0,0,0); \
  acc[2][ntI] = __builtin_amdgcn_mfma_f32_16x16x32_bf16(ax[2], bx, acc[2][ntI], 0,0,0); \
  acc[3][ntI] = __builtin_amdgcn_mfma_f32_16x16x32_bf16(ax[3], bx, acc[3][ntI], 0,0,0);

// swizzled LDS B-fragment reads (row stride 2304B for L0-K=1152, 4096B for L1)
#define LDSB0(ntI, kb) (*(const bhalf8*)(smem + ((ntI)*16 + l15)*2304 + ((kb) ^ swz)))
#define LDSB1(ntI, kb) (*(const bhalf8*)(smem + ((ntI)*16 + l15)*4096 + ((kb) ^ swz)))

// L0 h-part pipelined iteration (8 iters/wave, depth-4, issue-after-consume)
#define L0H(i) { \
  waitvm<((i) <= 4 ? 12 : 4*(7-(i)))>(); \
  ATIE((i)&3); \
  { const int kb = 256 + ks*512 + (i)*64 + l4*16; \
    bhalf8 bv0 = LDSB0(0, kb); bhalf8 bv1 = LDSB0(1, kb); \
    bhalf8 bv2 = LDSB0(2, kb); bhalf8 bv3 = LDSB0(3, kb); \
    MFMA4(0, bv0, (i)&3); MFMA4(1, bv1, (i)&3); \
    MFMA4(2, bv2, (i)&3); MFMA4(3, bv3, (i)&3); } \
  if ((i) + 4 < 8) { \
    GLOADA(af[(i)&3][0], abase0 + ((i)+4)*32); \
    GLOADA(af[(i)&3][1], abase1 + ((i)+4)*32); \
    GLOADA(af[(i)&3][2], abase2 + ((i)+4)*32); \
    GLOADA(af[(i)&3][3], abase3 + ((i)+4)*32); } \
}

// L1 pipelined iteration (16 iters/wave)
#define L1H(i) { \
  waitvm<((i) <= 12 ? 12 : 4*(15-(i)))>(); \
  ATIE((i)&3); \
  { const int kb = ks*1024 + (i)*64 + l4*16; \
    bhalf8 bv0 = LDSB1(0, kb); bhalf8 bv1 = LDSB1(1, kb); \
    MFMA4(0, bv0, (i)&3); MFMA4(1, bv1, (i)&3); } \
  if ((i) + 4 < 16) { \
    GLOADA(af[(i)&3][0], abase0 + ((i)+4)*32); \
    GLOADA(af[(i)&3][1], abase1 + ((i)+4)*32); \
    GLOADA(af[(i)&3][2], abase2 + ((i)+4)*32); \
    GLOADA(af[(i)&3][3], abase3 + ((i)+4)*32); } \
}

__global__ __launch_bounds__(256, 1) void gru_persist(
    const float* __restrict__ x,  const float* __restrict__ W0,
    const float* __restrict__ b0, const float* __restrict__ W1,
    const float* __restrict__ b1, char* __restrict__ ws)
{
  extern __shared__ char smem[];
  const int tid  = threadIdx.x;
  const int lane = tid & 63;
  const int ks   = tid >> 6;       // wave id = K-slice id = owned M-tile
  const int l4   = lane >> 4;
  const int l15  = lane & 15;
  const int swz  = (l15 & 7) << 4; // row&7 == l15&7 for rows nt*16+l15
  const int wg   = blockIdx.x;
  const bool isL0 = wg < 64;

  unsigned short* h0b = (unsigned short*)(ws + WS_H0B);
  unsigned short* h1b = (unsigned short*)(ws + WS_H1B);
  float*          h1f = (float*)(ws + WS_H1F);
  unsigned int*   bar = (unsigned int*)ws;

  int g, blk;
  if (isL0) { g = wg & 1; blk = wg >> 1; }
  else      { int idx = wg - 64; g = idx & 1; blk = idx >> 1; }

  // ---- one-time: stage weight slice into LDS (bf16, [n][k], swizzled) ----
  if (isL0) {
    const int n   = lane;  // 64 rows: 0..31 z-cols, 32..63 n-gate cols
    const int col = (n < 32) ? (blk*32 + n) : (2048 + blk*32 + (n - 32));
    for (int it = 0; it < 288; ++it) {
      const int k = ks*288 + it;
      unsigned int u = bfbits(W0[(size_t)k*3072 + col]);
      *(unsigned short*)(smem + n*2304 + ((2*k) ^ ((n & 7) << 4))) = (unsigned short)u;
    }
  } else {
    const int n   = lane & 31; // 32 rows: 0..15 z, 16..31 n-gate
    const int col = (n < 16) ? (blk*16 + n) : (2048 + blk*16 + (n - 16));
    for (int it = 0; it < 256; ++it) {
      const int k = ks*512 + it*2 + (lane >> 5);
      unsigned int u = bfbits(W1[(size_t)k*3072 + col]);
      *(unsigned short*)(smem + n*4096 + ((2*k) ^ ((n & 7) << 4))) = (unsigned short)u;
    }
  }
  __syncthreads();

  float biasv[4] = {0.f, 0.f, 0.f, 0.f};
  if (isL0) {
    biasv[0] = b0[blk*32 + l15];
    biasv[1] = b0[blk*32 + 16 + l15];
    biasv[2] = b0[2048 + blk*32 + l15];
    biasv[3] = b0[2048 + blk*32 + 16 + l15];
  } else {
    biasv[0] = b1[blk*16 + l15];
    biasv[1] = b1[2048 + blk*16 + l15];
  }

  // h_old for this wave's owned (M-tile ks x our columns), lives in regs
  float hp[2][4] = {{0.f,0.f,0.f,0.f},{0.f,0.f,0.f,0.f}};

  for (int p = 0; p <= SEQLEN; ++p) {
    if (isL0) {
      if (p < SEQLEN) {
        const int t = p;
        const unsigned short* h0in  = h0b + (size_t)((t+1)&1)*131072;
        unsigned short*       h0out = h0b + (size_t)(t&1)*131072;

        f32x4 acc[4][4];
        #pragma unroll
        for (int mt = 0; mt < 4; ++mt)
          #pragma unroll
          for (int nt = 0; nt < 4; ++nt)
            #pragma unroll
            for (int r = 0; r < 4; ++r)
              acc[mt][nt][r] = (ks == 0) ? biasv[nt] : 0.0f;

        // ---- x contribution: wave ks takes x K-slice [ks*32, ks*32+32) ----
        {
          bhalf8 ax[4];
          #pragma unroll
          for (int mt = 0; mt < 4; ++mt) {
            const int b = g*64 + mt*16 + l15;
            const float* xp = x + ((size_t)b*SEQLEN + t)*INDIM + ks*32 + l4*8;
            f32x4 lo = *(const f32x4*)xp;
            f32x4 hi = *(const f32x4*)(xp + 4);
            #pragma unroll
            for (int e = 0; e < 4; ++e) {
              ax[mt][e]   = (short)bfbits(lo[e]);
              ax[mt][4+e] = (short)bfbits(hi[e]);
            }
          }
          const int kb = ks*64 + l4*16;
          bhalf8 bv0 = LDSB0(0, kb); bhalf8 bv1 = LDSB0(1, kb);
          bhalf8 bv2 = LDSB0(2, kb); bhalf8 bv3 = LDSB0(3, kb);
          MFMA4X(0, bv0); MFMA4X(1, bv1); MFMA4X(2, bv2); MFMA4X(3, bv3);
        }

        // ---- h0 contribution: wave ks takes h K-slice [ks*256, ks*256+256) ----
        const int bb = g*64 + l15;
        const unsigned short* abase0 = h0in + (size_t)(bb +  0)*1024 + ks*256 + l4*8;
        const unsigned short* abase1 = h0in + (size_t)(bb + 16)*1024 + ks*256 + l4*8;
        const unsigned short* abase2 = h0in + (size_t)(bb + 32)*1024 + ks*256 + l4*8;
        const unsigned short* abase3 = h0in + (size_t)(bb + 48)*1024 + ks*256 + l4*8;
        bhalf8 af[4][4];
        GLOADA(af[0][0], abase0 +  0); GLOADA(af[0][1], abase1 +  0);
        GLOADA(af[0][2], abase2 +  0); GLOADA(af[0][3], abase3 +  0);
        GLOADA(af[1][0], abase0 + 32); GLOADA(af[1][1], abase1 + 32);
        GLOADA(af[1][2], abase2 + 32); GLOADA(af[1][3], abase3 + 32);
        GLOADA(af[2][0], abase0 + 64); GLOADA(af[2][1], abase1 + 64);
        GLOADA(af[2][2], abase2 + 64); GLOADA(af[2][3], abase3 + 64);
        GLOADA(af[3][0], abase0 + 96); GLOADA(af[3][1], abase1 + 96);
        GLOADA(af[3][2], abase2 + 96); GLOADA(af[3][3], abase3 + 96);
        L0H(0) L0H(1) L0H(2) L0H(3) L0H(4) L0H(5) L0H(6) L0H(7)

        // ---- cross-wave K reduction: wave q gathers M-tile q ----
        float* st = (float*)(smem + 147456);
        f32x4 gacc[4];
        #pragma unroll
        for (int q = 0; q < 4; ++q) {
          __syncthreads();
          #pragma unroll
          for (int nt = 0; nt < 4; ++nt)
            #pragma unroll
            for (int r = 0; r < 4; ++r)
              st[ks*1024 + nt*256 + (l4*4+r)*16 + l15] = acc[q][nt][r];
          __syncthreads();
          if (ks == q) {
            #pragma unroll
            for (int nt = 0; nt < 4; ++nt)
              #pragma unroll
              for (int r = 0; r < 4; ++r)
                gacc[nt][r] = st[       nt*256 + (l4*4+r)*16 + l15]
                            + st[1024 + nt*256 + (l4*4+r)*16 + l15]
                            + st[2048 + nt*256 + (l4*4+r)*16 + l15]
                            + st[3072 + nt*256 + (l4*4+r)*16 + l15];
          }
        }

        // ---- eltwise: h0_new = n + z*(h_old - n); pairs (z:nt, n:nt+2) ----
        #pragma unroll
        for (int pi = 0; pi < 2; ++pi)
          #pragma unroll
          for (int r = 0; r < 4; ++r) {
            const float z  = 1.0f/(1.0f + __expf(-gacc[pi][r]));
            const float e2 = __expf(2.0f*gacc[pi+2][r]);
            const float n  = (e2 - 1.0f)/(e2 + 1.0f);
            const float hn = n + z*(hp[pi][r] - n);
            hp[pi][r] = hn;
            const int j = blk*32 + pi*16 + l15;
            const int b = g*64 + ks*16 + l4*4 + r;
            STORE_BF16(h0out + (size_t)b*1024 + j, bfbits(hn));
          }
      }
    } else {
      if (p > 0) {
        const int t = p - 1;
        const unsigned short* h0in  = h0b + (size_t)(t&1)*131072;
        const unsigned short* h1in  = h1b + (size_t)((t+1)&1)*131072;
        unsigned short*       h1out = h1b + (size_t)(t&1)*131072;

        f32x4 acc[4][2];
        #pragma unroll
        for (int mt = 0; mt < 4; ++mt)
          #pragma unroll
          for (int nt = 0; nt < 2; ++nt)
            #pragma unroll
            for (int r = 0; r < 4; ++r)
              acc[mt][nt][r] = (ks == 0) ? biasv[nt] : 0.0f;

        // waves 0,1 -> h0 K-halves; waves 2,3 -> h1 K-halves
        const unsigned short* asrc = (ks < 2) ? h0in : h1in;
        const int bb = g*64 + l15;
        const unsigned short* abase0 = asrc + (size_t)(bb +  0)*1024 + (ks&1)*512 + l4*8;
        const unsigned short* abase1 = asrc + (size_t)(bb + 16)*1024 + (ks&1)*512 + l4*8;
        const unsigned short* abase2 = asrc + (size_t)(bb + 32)*1024 + (ks&1)*512 + l4*8;
        const unsigned short* abase3 = asrc + (size_t)(bb + 48)*1024 + (ks&1)*512 + l4*8;
        bhalf8 af[4][4];
        GLOADA(af[0][0], abase0 +  0); GLOADA(af[0][1], abase1 +  0);
        GLOADA(af[0][2], abase2 +  0); GLOADA(af[0][3], abase3 +  0);
        GLOADA(af[1][0], abase0 + 32); GLOADA(af[1][1], abase1 + 32);
        GLOADA(af[1][2], abase2 + 32); GLOADA(af[1][3], abase3 + 32);
        GLOADA(af[2][0], abase0 + 64); GLOADA(af[2][1], abase1 + 64);
        GLOADA(af[2][2], abase2 + 64); GLOADA(af[2][3], abase3 + 64);
        GLOADA(af[3][0], abase0 + 96); GLOADA(af[3][1], abase1 + 96);
        GLOADA(af[3][2], abase2 + 96); GLOADA(af[3][3], abase3 + 96);
        L1H(0)  L1H(1)  L1H(2)  L1H(3)  L1H(4)  L1H(5)  L1H(6)  L1H(7)
        L1H(8)  L1H(9)  L1H(10) L1H(11) L1H(12) L1H(13) L1H(14) L1H(15)

        float* st = (float*)(smem + 131072);
        f32x4 gacc[2];
        #pragma unroll
        for (int q = 0; q < 4; ++q) {
          __syncthreads();
          #pragma unroll
          for (int nt = 0; nt < 2; ++nt)
            #pragma unroll
            for (int r = 0; r < 4; ++r)
              st[ks*512 + nt*256 + (l4*4+r)*16 + l15] = acc[q][nt][r];
          __syncthreads();
          if (ks == q) {
            #pragma unroll
            for (int nt = 0; nt < 2; ++nt)
              #pragma unroll
              for (int r = 0; r < 4; ++r)
                gacc[nt][r] = st[       nt*256 + (l4*4+r)*16 + l15]
                            + st[ 512 + nt*256 + (l4*4+r)*16 + l15]
                            + st[1024 + nt*256 + (l4*4+r)*16 + l15]
                            + st[1536 + nt*256 + (l4*4+r)*16 + l15];
          }
        }

        #pragma unroll
        for (int r = 0; r < 4; ++r) {
          const float z  = 1.0f/(1.0f + __expf(-gacc[0][r]));
          const float e2 = __expf(2.0f*gacc[1][r]);
          const float n  = (e2 - 1.0f)/(e2 + 1.0f);
          const float hn = n + z*(hp[0][r] - n);
          hp[0][r] = hn;
          const int j = blk*16 + l15;
          const int b = g*64 + ks*16 + l4*4 + r;
          STORE_BF16(h1out + (size_t)b*1024 + j, bfbits(hn));
          STORE_F32(h1f + (size_t)b*1024 + j, hn);
        }
      }
    }

    // ---- global phase barrier (monotonic counters, LLC scope) ----
    asm volatile("s_waitcnt vmcnt(0) lgkmcnt(0)" ::: "memory");
    __syncthreads();
    if (tid == 0) {
      __hip_atomic_fetch_add(&bar[(wg & 7)*32], 1u, __ATOMIC_RELAXED, __HIP_MEMORY_SCOPE_AGENT);
      const unsigned int target = 24u * (unsigned int)(p + 1);
      for (;;) {
        unsigned int mn = 0xffffffffu;
        #pragma unroll
        for (int c = 0; c < 8; ++c) {
          unsigned int v = __hip_atomic_load(&bar[c*32], __ATOMIC_RELAXED, __HIP_MEMORY_SCOPE_AGENT);
          mn = (v < mn) ? v : mn;
        }
        if (mn >= target) break;
        __builtin_amdgcn_s_sleep(1);
      }
    }
    __syncthreads();
  }
}

__global__ void gru_pred(const char* __restrict__ ws, const float* __restrict__ Wfc,
                         const float* __restrict__ bfc, float* __restrict__ out)
{
  const int b = blockIdx.x;
  const int l = threadIdx.x;   // 64 threads = 1 wave per batch row
  const float* h = (const float*)(ws + WS_H1F) + (size_t)b*1024;
  float s = 0.0f;
  for (int k = l; k < 1024; k += 64) s += h[k] * Wfc[k];
  #pragma unroll
  for (int off = 32; off > 0; off >>= 1) s += __shfl_down(s, off);
  if (l == 0) out[b] = s + bfc[0];
}

extern "C" void kernel_launch(void* const* d_in, const int* in_sizes, int n_in,
                              void* d_out, int out_size, void* d_ws, size_t ws_size,
                              hipStream_t stream)
{
  (void)in_sizes; (void)n_in; (void)out_size; (void)ws_size;
  const float* x   = (const float*)d_in[0];
  const float* W0  = (const float*)d_in[1];
  const float* b0  = (const float*)d_in[2];
  const float* W1  = (const float*)d_in[3];
  const float* b1  = (const float*)d_in[4];
  const float* Wfc = (const float*)d_in[5];
  const float* bfc = (const float*)d_in[6];
  char* ws = (char*)d_ws;

  hipFuncSetAttribute(reinterpret_cast<const void*>(gru_persist),
                      hipFuncAttributeMaxDynamicSharedMemorySize, LDS_BYTES);
  hipMemsetAsync(ws, 0, WS_END, stream);   // h buffers + barrier counters = 0
  hipLaunchKernelGGL(gru_persist, dim3(192), dim3(256), LDS_BYTES, stream,
                     x, W0, b0, W1, b1, ws);
  hipLaunchKernelGGL(gru_pred, dim3(128), dim3(64), 0, stream,
                     ws, Wfc, bfc, (float*)d_out);
}